// Round 2
// baseline (129.996 us; speedup 1.0000x reference)
//
#include <hip/hip_runtime.h>
#include <cstdint>

// Problem: B=4, IC=OC=64, H=W=32, K=3, PAD=1
// Outputs: new_x (262144 f32), new_q (262144 f32) concatenated.
//
// Math (derived from reference):
//   a0 = conv3x3(x,W,pad=1)+bias ; p0 = sigmoid(a0)
//   new_x = 2*(u < p0) - 1,  u = JAX threefry2x32-20 uniforms, key=(0,42),
//           PARTITIONABLE counter mode: element i -> threefry(key,(i>>32, i)),
//           32-bit draw = bits1 ^ bits2 (xor-fold of the two output words).
//   new_q = 2*new_x*( s1*C1 - s2*C2 )   [2nd-order Taylor in delta=2xW, |2W|<=0.145,
//                                        truncation error ~4e-5 << 0.02 threshold]
//   where s1 = p0(1-p0), s2 = s1(1-2p0),
//         C1 = conv3x3(x*q, W, pad=1), C2 = conv3x3(q, W*W, pad=1)
//
// a0/p0 path in float64: x is exactly +-1 so products are exact; any f64
// summation order agrees with an np-f64 reference to ~1e-12, making
// u-vs-p0 borderline flips (P ~ 1e-3 over all 262144 pixels) negligible.

static constexpr int XQ_ELEMS = 4 * 34 * 34 * 64;        // padded float2 tensor [b][h'][w'][ic]
static constexpr int U_OFF_F  = XQ_ELEMS * 2;            // float offset of u[262144]
static constexpr int WT_OFF_F = U_OFF_F + 262144;        // float offset of wt[64][9][64]
// total ws use: 890880 floats = 3,563,520 bytes

__device__ __forceinline__ uint32_t rotl32(uint32_t v, int n) {
  return (v << n) | (v >> (32 - n));
}

// ---------------- prep: pad+transpose (x,q), threefry uniforms, transpose W ---------
__global__ __launch_bounds__(256) void prep_kernel(
    const float* __restrict__ x, const float* __restrict__ q,
    const float* __restrict__ weight, float* __restrict__ ws) {
  int idx = blockIdx.x * 256 + threadIdx.x;
  float2* xq = (float2*)ws;
  float* u  = ws + U_OFF_F;
  float* wt = ws + WT_OFF_F;

  if (idx < XQ_ELEMS) {
    // layout: (((b*34 + hp)*34 + wp)*64 + ic), border (hp/wp==0 or 33) = zeros
    int ic = idx & 63;
    int t  = idx >> 6;
    int wp = t % 34;
    int t2 = t / 34;
    int hp = t2 % 34;
    int b  = t2 / 34;
    float xv = 0.f, qv = 0.f;
    if (hp >= 1 && hp <= 32 && wp >= 1 && wp <= 32) {
      int src = ((b * 64 + ic) * 32 + (hp - 1)) * 32 + (wp - 1);
      xv = x[src];
      qv = q[src];
    }
    xq[idx] = make_float2(xv, qv);
  } else if (idx < XQ_ELEMS + 262144) {
    // JAX threefry2x32-20, key=(0,42), partitionable counter mode:
    // element j: counter words (hi,lo) = (0, j)  [j < 2^32]
    uint32_t j  = (uint32_t)(idx - XQ_ELEMS);
    uint32_t x0 = 0u, x1 = j;
    const uint32_t ks0 = 0u, ks1 = 42u, ks2 = 0x1BD11BDAu ^ 42u;
    x0 += ks0; x1 += ks1;
#define QR(rot) { x0 += x1; x1 = rotl32(x1, rot); x1 ^= x0; }
    QR(13) QR(15) QR(26) QR(6)
    x0 += ks1; x1 += ks2 + 1u;
    QR(17) QR(29) QR(16) QR(24)
    x0 += ks2; x1 += ks0 + 2u;
    QR(13) QR(15) QR(26) QR(6)
    x0 += ks0; x1 += ks1 + 3u;
    QR(17) QR(29) QR(16) QR(24)
    x0 += ks1; x1 += ks2 + 4u;
    QR(13) QR(15) QR(26) QR(6)
    x0 += ks2; x1 += ks0 + 5u;
#undef QR
    uint32_t bits = x0 ^ x1;   // 32-bit draw = xor-fold of the two output words
    u[j] = __uint_as_float((bits >> 9) | 0x3F800000u) - 1.0f;
  } else if (idx < XQ_ELEMS + 262144 + 36864) {
    // wt[(oc*9 + kh*3 + kw)*64 + ic] = weight[oc][ic][kh][kw]
    int k  = idx - (XQ_ELEMS + 262144);
    int ic = k & 63;
    int t  = k >> 6;            // oc*9 + tap
    int tap = t % 9;
    int oc  = t / 9;
    int kh = tap / 3, kw = tap % 3;
    wt[k] = weight[((oc * 64 + ic) * 3 + kh) * 3 + kw];
  }
}

// ---------------- DPP wave64 reduction (stays on VALU pipe) -------------------------
template <int CTRL>
__device__ __forceinline__ float dppadd(float v) {
  int t = __builtin_amdgcn_update_dpp(0, __float_as_int(v), CTRL, 0xf, 0xf, true);
  return v + __int_as_float(t);
}

__device__ __forceinline__ void wsum2(float& a, float& b) {
  a = dppadd<0x111>(a); b = dppadd<0x111>(b);  // row_shr:1
  a = dppadd<0x112>(a); b = dppadd<0x112>(b);  // row_shr:2
  a = dppadd<0x114>(a); b = dppadd<0x114>(b);  // row_shr:4
  a = dppadd<0x118>(a); b = dppadd<0x118>(b);  // row_shr:8
  a = dppadd<0x142>(a); b = dppadd<0x142>(b);  // row_bcast:15
  a = dppadd<0x143>(a); b = dppadd<0x143>(b);  // row_bcast:31
  a = __int_as_float(__builtin_amdgcn_readlane(__float_as_int(a), 63));
  b = __int_as_float(__builtin_amdgcn_readlane(__float_as_int(b), 63));
}

// ---------------- main: 1 wave per (b,oc,h) row, lane = ic --------------------------
__global__ __launch_bounds__(256) void main_kernel(
    const float* __restrict__ ws_ro, const float* __restrict__ bias,
    float* __restrict__ out) {
  const float2* xq = (const float2*)ws_ro;
  const float* u  = ws_ro + U_OFF_F;
  const float* wt = ws_ro + WT_OFF_F;

  int lane = threadIdx.x & 63;
  int wid  = (blockIdx.x * 256 + threadIdx.x) >> 6;   // 8192 waves
  int oc = wid & 63;
  int bh = wid >> 6;
  int h  = bh & 31;
  int b  = bh >> 5;

  float W[9], W2[9];
  double Wd[9];
  {
    const float* wp = wt + oc * 576 + lane;
#pragma unroll
    for (int k = 0; k < 9; ++k) {
      float v = wp[k * 64];
      W[k] = v;
      W2[k] = v * v;
      Wd[k] = (double)v;
    }
  }
  double bod = (double)bias[oc];
  // lanes 0..31 hold this row's 32 uniforms (broadcast later via readlane)
  float urow = u[((b * 64 + oc) * 32 + h) * 32 + (lane & 31)];

  const float2* colbase = xq + (size_t)((b * 34 + h) * 34) * 64 + lane;

  // sliding 3x3 window of (x,q); slot s always holds the latest col c with c%3==s
  float2 win[3][3];
#pragma unroll
  for (int r = 0; r < 3; ++r) {
    win[r][0] = colbase[(r * 34 + 0) * 64];
    win[r][1] = colbase[(r * 34 + 1) * 64];
  }

  float keep_x = 0.f, keep_q = 0.f;
  for (int wg = 0; wg < 33; wg += 3) {   // 33 px; w=32 is harmless overrun (never kept)
#pragma unroll
    for (int sub = 0; sub < 3; ++sub) {
      const int w  = wg + sub;
      const int sl = (sub + 2) % 3;
#pragma unroll
      for (int r = 0; r < 3; ++r)
        win[r][sl] = colbase[(r * 34 + (w + 2)) * 64];

      double a0p = 0.0;
      float c1p = 0.f, c2p = 0.f;
#pragma unroll
      for (int r = 0; r < 3; ++r) {
#pragma unroll
        for (int kw = 0; kw < 3; ++kw) {
          float2 v = win[r][(sub + kw) % 3];
          const int t = r * 3 + kw;
          a0p = fma((double)v.x, Wd[t], a0p);
          c1p = fmaf(v.x * v.y, W[t], c1p);
          c2p = fmaf(v.y, W2[t], c2p);
        }
      }
      // f64 butterfly reduction for a0 (all lanes end with the sum)
#pragma unroll
      for (int m = 32; m >= 1; m >>= 1) a0p += __shfl_xor(a0p, m, 64);
      wsum2(c1p, c2p);

      double A0 = a0p + bod;
      double p0d = 1.0 / (1.0 + exp(-A0));
      float su = __int_as_float(__builtin_amdgcn_readlane(__float_as_int(urow), w));
      float nx = ((double)su < p0d) ? 1.0f : -1.0f;
      float p0 = (float)p0d;
      float s1 = p0 * (1.0f - p0);
      float s2 = s1 * (1.0f - 2.0f * p0);
      float dq = 2.0f * nx * (s1 * c1p - s2 * c2p);
      if (lane == w) { keep_x = nx; keep_q = dq; }
    }
  }

  if (lane < 32) {
    int o = ((b * 64 + oc) * 32 + h) * 32 + lane;
    out[o] = keep_x;
    out[262144 + o] = keep_q;
  }
}

extern "C" void kernel_launch(void* const* d_in, const int* in_sizes, int n_in,
                              void* d_out, int out_size, void* d_ws, size_t ws_size,
                              hipStream_t stream) {
  const float* x      = (const float*)d_in[0];
  const float* q      = (const float*)d_in[1];
  const float* weight = (const float*)d_in[2];
  const float* bias   = (const float*)d_in[3];
  float* out = (float*)d_out;
  float* ws  = (float*)d_ws;

  // prep: 295936 xq + 262144 threefry + 36864 wt = 594944 items = 2324 * 256
  prep_kernel<<<2324, 256, 0, stream>>>(x, q, weight, ws);
  // main: 8192 waves (b,oc,h) * 64 lanes = 2048 blocks * 256
  main_kernel<<<2048, 256, 0, stream>>>(ws, bias, out);
}

// Round 3
// 103.027 us; speedup vs baseline: 1.2618x; 1.2618x over previous
//
#include <hip/hip_runtime.h>
#include <cstdint>

// Problem: B=4, IC=OC=64, H=W=32, K=3, PAD=1
// Outputs: new_x (262144 f32), new_q (262144 f32) concatenated.
//
// Math (derived from reference):
//   a0 = conv3x3(x,W,pad=1)+bias ; p0 = sigmoid(a0)
//   new_x = 2*(u < p0) - 1,  u = JAX threefry2x32-20 uniforms, key=(0,42),
//           PARTITIONABLE counter mode: element i -> threefry(key,(0, i)),
//           32-bit draw = bits1 ^ bits2 (xor-fold).           [verified round 2]
//   new_q = 2*new_x*( s1*C1 - s2*C2 )   [2nd-order Taylor in delta=2xW, |2W|<=0.145,
//                                        truncation error ~4e-5 << 0.02 threshold]
//   where s1 = p0(1-p0), s2 = s1(1-2p0),
//         C1 = conv3x3(x*q, W, pad=1), C2 = conv3x3(q, W*W, pad=1)
//
// Round-3 structure: per-pixel (a0,c1,c2) are reduced across lanes (ic) with
// pure-VALU DPP (no ds_bpermute -> no LDS pipe), kept in lane w via cndmask;
// the f64 sigmoid runs ONCE per pixel in the epilogue (lane-parallel), not
// 33x redundantly inside the loop.

static constexpr int XQ_ELEMS = 4 * 34 * 34 * 64;        // padded float2 tensor [b][h'][w'][ic]
static constexpr int U_OFF_F  = XQ_ELEMS * 2;            // float offset of u[262144]
static constexpr int WT_OFF_F = U_OFF_F + 262144;        // float offset of wt[64][9][64]

__device__ __forceinline__ uint32_t rotl32(uint32_t v, int n) {
  return (v << n) | (v >> (32 - n));
}

// ---------------- prep: pad+transpose (x,q), threefry uniforms, transpose W ---------
// ranges (idx): [0,262144) interior xq (src-ordered, coalesced reads)
//               [262144, 296?) border zeros (33792)
//               then 262144 threefry, then 36864 weight transpose
__global__ __launch_bounds__(256) void prep_kernel(
    const float* __restrict__ x, const float* __restrict__ q,
    const float* __restrict__ weight, float* __restrict__ ws) {
  int idx = blockIdx.x * 256 + threadIdx.x;
  float2* xq = (float2*)ws;
  float* u  = ws + U_OFF_F;
  float* wt = ws + WT_OFF_F;

  if (idx < 262144) {
    // src order: b,ic,h,w (w fastest) -> coalesced loads; scattered 8B writes
    int w  = idx & 31;
    int h  = (idx >> 5) & 31;
    int ic = (idx >> 10) & 63;
    int b  = idx >> 16;
    float2 v = make_float2(x[idx], q[idx]);
    xq[(((b * 34 + h + 1) * 34) + (w + 1)) * 64 + ic] = v;
  } else if (idx < 262144 + 33792) {
    // border zeros: per b, 132 border cells x 64 ic
    int k = idx - 262144;
    int b = k / 8448;
    int r = k - b * 8448;
    int cell = r >> 6;
    int ic = r & 63;
    int hp, wp;
    if (cell < 34)       { hp = 0;          wp = cell; }
    else if (cell < 68)  { hp = 33;         wp = cell - 34; }
    else if (cell < 100) { hp = cell - 67;  wp = 0; }       // hp in 1..32
    else                 { hp = cell - 99;  wp = 33; }      // hp in 1..32
    xq[((b * 34 + hp) * 34 + wp) * 64 + ic] = make_float2(0.f, 0.f);
  } else if (idx < 262144 + 33792 + 262144) {
    // JAX threefry2x32-20, key=(0,42), partitionable counter mode:
    // element j: counter words (hi,lo) = (0, j); draw = out0 ^ out1
    uint32_t j  = (uint32_t)(idx - (262144 + 33792));
    uint32_t x0 = 0u, x1 = j;
    const uint32_t ks0 = 0u, ks1 = 42u, ks2 = 0x1BD11BDAu ^ 42u;
    x0 += ks0; x1 += ks1;
#define QR(rot) { x0 += x1; x1 = rotl32(x1, rot); x1 ^= x0; }
    QR(13) QR(15) QR(26) QR(6)
    x0 += ks1; x1 += ks2 + 1u;
    QR(17) QR(29) QR(16) QR(24)
    x0 += ks2; x1 += ks0 + 2u;
    QR(13) QR(15) QR(26) QR(6)
    x0 += ks0; x1 += ks1 + 3u;
    QR(17) QR(29) QR(16) QR(24)
    x0 += ks1; x1 += ks2 + 4u;
    QR(13) QR(15) QR(26) QR(6)
    x0 += ks2; x1 += ks0 + 5u;
#undef QR
    uint32_t bits = x0 ^ x1;
    u[j] = __uint_as_float((bits >> 9) | 0x3F800000u) - 1.0f;
  } else if (idx < 262144 + 33792 + 262144 + 36864) {
    // wt[(oc*9 + kh*3 + kw)*64 + ic] = weight[oc][ic][kh][kw]
    int k  = idx - (262144 + 33792 + 262144);
    int ic = k & 63;
    int t  = k >> 6;            // oc*9 + tap
    int tap = t % 9;
    int oc  = t / 9;
    int kh = tap / 3, kw = tap % 3;
    wt[k] = weight[((oc * 64 + ic) * 3 + kh) * 3 + kw];
  }
}

// ---------------- DPP reductions (VALU pipe only; sequence verified in round 2) -----
template <int CTRL>
__device__ __forceinline__ float dppadd(float v) {
  int t = __builtin_amdgcn_update_dpp(0, __float_as_int(v), CTRL, 0xf, 0xf, true);
  return v + __int_as_float(t);
}

template <int CTRL>
__device__ __forceinline__ double dppadd64(double v) {
  union { double d; int i[2]; } s, t;
  s.d = v;
  t.i[0] = __builtin_amdgcn_update_dpp(0, s.i[0], CTRL, 0xf, 0xf, true);
  t.i[1] = __builtin_amdgcn_update_dpp(0, s.i[1], CTRL, 0xf, 0xf, true);
  return v + t.d;
}

__device__ __forceinline__ double rdlane64(double v, int lane) {
  union { double d; int i[2]; } s;
  s.d = v;
  s.i[0] = __builtin_amdgcn_readlane(s.i[0], lane);
  s.i[1] = __builtin_amdgcn_readlane(s.i[1], lane);
  return s.d;
}

// reduce a0 (f64) + c1,c2 (f32) across the wave; return totals (valid everywhere)
__device__ __forceinline__ void wreduce(double& a, float& b, float& c) {
  a = dppadd64<0x111>(a); b = dppadd<0x111>(b); c = dppadd<0x111>(c);  // row_shr:1
  a = dppadd64<0x112>(a); b = dppadd<0x112>(b); c = dppadd<0x112>(c);  // row_shr:2
  a = dppadd64<0x114>(a); b = dppadd<0x114>(b); c = dppadd<0x114>(c);  // row_shr:4
  a = dppadd64<0x118>(a); b = dppadd<0x118>(b); c = dppadd<0x118>(c);  // row_shr:8
  a = dppadd64<0x142>(a); b = dppadd<0x142>(b); c = dppadd<0x142>(c);  // row_bcast:15
  a = dppadd64<0x143>(a); b = dppadd<0x143>(b); c = dppadd<0x143>(c);  // row_bcast:31
  a = rdlane64(a, 63);
  b = __int_as_float(__builtin_amdgcn_readlane(__float_as_int(b), 63));
  c = __int_as_float(__builtin_amdgcn_readlane(__float_as_int(c), 63));
}

// ---------------- main: 1 wave per (b,oc,h) row, lane = ic --------------------------
__global__ __launch_bounds__(256) void main_kernel(
    const float* __restrict__ ws_ro, const float* __restrict__ bias,
    float* __restrict__ out) {
  const float2* xq = (const float2*)ws_ro;
  const float* u  = ws_ro + U_OFF_F;
  const float* wt = ws_ro + WT_OFF_F;

  int lane = threadIdx.x & 63;
  int wid  = (blockIdx.x * 256 + threadIdx.x) >> 6;   // 8192 waves
  int oc = wid & 63;
  int bh = wid >> 6;
  int h  = bh & 31;
  int b  = bh >> 5;

  float W[9], W2[9];
  double Wd[9];
  {
    const float* wp = wt + oc * 576 + lane;
#pragma unroll
    for (int k = 0; k < 9; ++k) {
      float v = wp[k * 64];
      W[k] = v;
      W2[k] = v * v;
      Wd[k] = (double)v;
    }
  }
  double bod = (double)bias[oc];
  // lane w (w<32) holds its own pixel's uniform
  float urow = u[((b * 64 + oc) * 32 + h) * 32 + (lane & 31)];

  const float2* colbase = xq + (size_t)((b * 34 + h) * 34) * 64 + lane;

  // sliding 3x3 window of (x,q); slot s always holds the latest col c with c%3==s
  float2 win[3][3];
#pragma unroll
  for (int r = 0; r < 3; ++r) {
    win[r][0] = colbase[(r * 34 + 0) * 64];
    win[r][1] = colbase[(r * 34 + 1) * 64];
  }

  double keepA = 0.0;
  float keep_c1 = 0.f, keep_c2 = 0.f;
  for (int wg = 0; wg < 33; wg += 3) {   // 33 px; w=32 is harmless overrun (never kept)
#pragma unroll
    for (int sub = 0; sub < 3; ++sub) {
      const int w  = wg + sub;
      const int sl = (sub + 2) % 3;
#pragma unroll
      for (int r = 0; r < 3; ++r)
        win[r][sl] = colbase[(r * 34 + (w + 2)) * 64];

      double a0p = 0.0;
      float c1p = 0.f, c2p = 0.f;
#pragma unroll
      for (int r = 0; r < 3; ++r) {
#pragma unroll
        for (int kw = 0; kw < 3; ++kw) {
          float2 v = win[r][(sub + kw) % 3];
          const int t = r * 3 + kw;
          a0p = fma((double)v.x, Wd[t], a0p);
          c1p = fmaf(v.x * v.y, W[t], c1p);
          c2p = fmaf(v.y, W2[t], c2p);
        }
      }
      wreduce(a0p, c1p, c2p);
      if (lane == w) { keepA = a0p; keep_c1 = c1p; keep_c2 = c2p; }
    }
  }

  // ---- epilogue: one f64 sigmoid per pixel, lane-parallel (lanes 0..31 live) ----
  double A0  = keepA + bod;
  double p0d = 1.0 / (1.0 + exp(-A0));
  float  p0  = (float)p0d;
  float  nx  = ((double)urow < p0d) ? 1.0f : -1.0f;
  float  s1  = p0 * (1.0f - p0);
  float  s2  = s1 * (1.0f - 2.0f * p0);
  float  dq  = 2.0f * nx * (s1 * keep_c1 - s2 * keep_c2);

  if (lane < 32) {
    int o = ((b * 64 + oc) * 32 + h) * 32 + lane;
    out[o] = nx;
    out[262144 + o] = dq;
  }
}

extern "C" void kernel_launch(void* const* d_in, const int* in_sizes, int n_in,
                              void* d_out, int out_size, void* d_ws, size_t ws_size,
                              hipStream_t stream) {
  const float* x      = (const float*)d_in[0];
  const float* q      = (const float*)d_in[1];
  const float* weight = (const float*)d_in[2];
  const float* bias   = (const float*)d_in[3];
  float* out = (float*)d_out;
  float* ws  = (float*)d_ws;

  // prep: 262144 interior + 33792 border + 262144 threefry + 36864 wt = 594944 = 2324*256
  prep_kernel<<<2324, 256, 0, stream>>>(x, q, weight, ws);
  // main: 8192 waves (b,oc,h) * 64 lanes = 2048 blocks * 256
  main_kernel<<<2048, 256, 0, stream>>>(ws, bias, out);
}

// Round 4
// 75.956 us; speedup vs baseline: 1.7115x; 1.3564x over previous
//
#include <hip/hip_runtime.h>
#include <cstdint>

// Problem: B=4, IC=OC=64, H=W=32, K=3, PAD=1
// Outputs: new_x (262144 f32), new_q (262144 f32) concatenated.
//
//   a0 = conv3x3(x,W,pad=1)+bias ; p0 = sigmoid(a0)
//   new_x = 2*(u < p0) - 1,  u = JAX threefry2x32-20, key=(0,42),
//           partitionable counter mode, draw = out0^out1   [verified r2]
//   new_q = 2*new_x*( s1*C1 - s2*C2 )   [2nd-order Taylor, err ~4e-5 << 2e-2]
//     s1 = p0(1-p0), s2 = s1(1-2p0),
//     C1 = conv3x3(x*q, W), C2 = conv3x3(q, W*W)
//
// Round 4: all three convs on MFMA.
//   a0: EXACT path — W split into 4 signed radix-256 digits of round(W*2^31);
//       x (+-1/0) as i8; 4x mfma_i32_16x16x64_i8 with exact i32 accumulation;
//       f64 reconstruction (digit sums < 2^42, exact in double).
//   C1/C2: mfma_f32_16x16x32_bf16 (bf16 rounding ~0.4% rel, harmless).
// Fragment layouts (guide, m89/m120-verified for 16x16 family):
//   A[m=lane&15][k=quad*(K/4)+j], B[k=quad*(K/4)+j][n=lane&15],
//   C/D: col(n)=lane&15, row(m)=quad*4+reg.

typedef __attribute__((ext_vector_type(4))) int   i32x4;
typedef __attribute__((ext_vector_type(8))) short s16x8;
typedef __attribute__((ext_vector_type(4))) float f32x4;

// ---- ws byte offsets ----
static constexpr int OFF_X8   = 0;          // i8  [b][34][34][64]   295,936 B
static constexpr int OFF_XQH  = 295936;     // bf16[b][34][34][64]   591,872 B
static constexpr int OFF_QH   = 887808;     // bf16[b][34][34][64]   591,872 B
static constexpr int OFF_WD   = 1479680;    // i8  [dig4][tap9][oc64][ic64] 147,456 B
static constexpr int OFF_WB   = 1627136;    // bf16[tap9][oc64][ic64] 73,728 B
static constexpr int OFF_W2B  = 1700864;    // bf16[tap9][oc64][ic64] 73,728 B
static constexpr int OFF_U    = 1774592;    // f32 [262144]         1,048,576 B
// total 2,823,168 B

__device__ __forceinline__ uint32_t rotl32(uint32_t v, int n) {
  return (v << n) | (v >> (32 - n));
}

__device__ __forceinline__ unsigned short f2bf(float f) {
  uint32_t u = __float_as_uint(f);
  uint32_t r = (u + 0x7FFFu + ((u >> 16) & 1u)) >> 16;   // RNE
  return (unsigned short)r;
}

// ---------------- prep: planes (dest-ordered, coalesced writes), threefry, digits ---
__global__ __launch_bounds__(256) void prep_kernel(
    const float* __restrict__ x, const float* __restrict__ q,
    const float* __restrict__ weight, char* __restrict__ ws) {
  int idx = blockIdx.x * 256 + threadIdx.x;

  if (idx < 295936) {
    // one thread per (b,hp,wp,ic), ic fastest -> coalesced 1B/2B/2B writes
    int ic = idx & 63;
    int t  = idx >> 6;
    int wp = t % 34;
    int t2 = t / 34;
    int hp = t2 % 34;
    int b  = t2 / 34;
    float xv = 0.f, qv = 0.f;
    if (hp >= 1 && hp <= 32 && wp >= 1 && wp <= 32) {
      int src = ((b * 64 + ic) * 32 + (hp - 1)) * 32 + (wp - 1);
      xv = x[src];
      qv = q[src];
    }
    ((char*)(ws + OFF_X8))[idx] = (char)(int)xv;                 // -1/0/+1
    ((unsigned short*)(ws + OFF_XQH))[idx] = f2bf(xv * qv);
    ((unsigned short*)(ws + OFF_QH))[idx]  = f2bf(qv);
  } else if (idx < 295936 + 262144) {
    // threefry2x32-20, key=(0,42), partitionable: counter (0,j), draw=out0^out1
    uint32_t j  = (uint32_t)(idx - 295936);
    uint32_t x0 = 0u, x1 = j;
    const uint32_t ks0 = 0u, ks1 = 42u, ks2 = 0x1BD11BDAu ^ 42u;
    x0 += ks0; x1 += ks1;
#define QR(rot) { x0 += x1; x1 = rotl32(x1, rot); x1 ^= x0; }
    QR(13) QR(15) QR(26) QR(6)
    x0 += ks1; x1 += ks2 + 1u;
    QR(17) QR(29) QR(16) QR(24)
    x0 += ks2; x1 += ks0 + 2u;
    QR(13) QR(15) QR(26) QR(6)
    x0 += ks0; x1 += ks1 + 3u;
    QR(17) QR(29) QR(16) QR(24)
    x0 += ks1; x1 += ks2 + 4u;
    QR(13) QR(15) QR(26) QR(6)
    x0 += ks2; x1 += ks0 + 5u;
#undef QR
    uint32_t bits = x0 ^ x1;
    ((float*)(ws + OFF_U))[j] = __uint_as_float((bits >> 9) | 0x3F800000u) - 1.0f;
  } else if (idx < 295936 + 262144 + 36864) {
    // one thread per (tap,oc,ic): k = tap*4096 + oc*64 + ic
    int k  = idx - (295936 + 262144);
    int ic = k & 63;
    int t  = k >> 6;
    int oc  = t & 63;
    int tap = t >> 6;
    int kh = tap / 3, kw = tap % 3;
    float Wv = weight[((oc * 64 + ic) * 3 + kh) * 3 + kw];
    long long wi = llrint((double)Wv * 2147483648.0);   // round(W * 2^31), |wi| < 2^28
    char* wd = ws + OFF_WD;
#pragma unroll
    for (int dig = 0; dig < 4; ++dig) {
      signed char d = (signed char)(wi & 0xFF);          // balanced low byte
      wd[dig * 36864 + k] = d;
      wi = (wi - (long long)d) >> 8;
    }
    ((unsigned short*)(ws + OFF_WB))[k]  = f2bf(Wv);
    ((unsigned short*)(ws + OFF_W2B))[k] = f2bf(Wv * Wv);
  }
}

// ---------------- main: MFMA convs + f64 sigmoid epilogue ---------------------------
// grid 256 = (b*32 + h)*2 + nt ; block 256 = 4 waves, wave = oc-tile (16 oc)
__global__ __launch_bounds__(256) void main_kernel(
    const char* __restrict__ ws, const float* __restrict__ bias,
    float* __restrict__ out) {
  const char* x8            = ws + OFF_X8;
  const unsigned short* xqh = (const unsigned short*)(ws + OFF_XQH);
  const unsigned short* qh  = (const unsigned short*)(ws + OFF_QH);
  const char* wd            = ws + OFF_WD;
  const unsigned short* wb  = (const unsigned short*)(ws + OFF_WB);
  const unsigned short* w2b = (const unsigned short*)(ws + OFF_W2B);
  const float* u            = (const float*)(ws + OFF_U);

  const int b  = blockIdx.x >> 6;
  const int h  = (blockIdx.x >> 1) & 31;
  const int nt = blockIdx.x & 1;

  const int octile = threadIdx.x >> 6;
  const int lane   = threadIdx.x & 63;
  const int quad   = lane >> 4;
  const int l16    = lane & 15;

  i32x4 accI[4];
#pragma unroll
  for (int d = 0; d < 4; ++d) accI[d] = (i32x4){0, 0, 0, 0};
  f32x4 aC1 = {0.f, 0.f, 0.f, 0.f};
  f32x4 aC2 = {0.f, 0.f, 0.f, 0.f};

  // A-operand element offsets (per-lane), add tap*4096 (+dig*36864 for i8)
  const int aoff_i8 = (octile * 16 + l16) * 64 + quad * 16;   // bytes into wd plane
  const int aoff_bf = (octile * 16 + l16) * 64 + quad * 8;    // ushort elements (+c*32)

#pragma unroll
  for (int kh = 0; kh < 3; ++kh) {
#pragma unroll
    for (int kw = 0; kw < 3; ++kw) {
      const int tap = kh * 3 + kw;
      // ---- A fragments (weights) ----
      i32x4 aI[4];
#pragma unroll
      for (int d = 0; d < 4; ++d)
        aI[d] = *(const i32x4*)(wd + d * 36864 + tap * 4096 + aoff_i8);
      s16x8 aW0 = *(const s16x8*)(wb  + tap * 4096 + aoff_bf);
      s16x8 aW1 = *(const s16x8*)(wb  + tap * 4096 + aoff_bf + 32);
      s16x8 aV0 = *(const s16x8*)(w2b + tap * 4096 + aoff_bf);
      s16x8 aV1 = *(const s16x8*)(w2b + tap * 4096 + aoff_bf + 32);
      // ---- B fragments (image), padded pixel (h+kh, w+kw) ----
      const int pix = ((b * 34 + h + kh) * 34 + (nt * 16 + l16 + kw)) * 64;
      i32x4 bI  = *(const i32x4*)(x8 + pix + quad * 16);
      s16x8 bX0 = *(const s16x8*)(xqh + pix + quad * 8);
      s16x8 bX1 = *(const s16x8*)(xqh + pix + 32 + quad * 8);
      s16x8 bQ0 = *(const s16x8*)(qh  + pix + quad * 8);
      s16x8 bQ1 = *(const s16x8*)(qh  + pix + 32 + quad * 8);
      // ---- MFMA ----
#pragma unroll
      for (int d = 0; d < 4; ++d)
        accI[d] = __builtin_amdgcn_mfma_i32_16x16x64_i8(aI[d], bI, accI[d], 0, 0, 0);
      aC1 = __builtin_amdgcn_mfma_f32_16x16x32_bf16(aW0, bX0, aC1, 0, 0, 0);
      aC1 = __builtin_amdgcn_mfma_f32_16x16x32_bf16(aW1, bX1, aC1, 0, 0, 0);
      aC2 = __builtin_amdgcn_mfma_f32_16x16x32_bf16(aV0, bQ0, aC2, 0, 0, 0);
      aC2 = __builtin_amdgcn_mfma_f32_16x16x32_bf16(aV1, bQ1, aC2, 0, 0, 0);
    }
  }

  // ---- epilogue: C/D col(n=px)=l16, row(m=oc)=quad*4+r ----
  const int w = nt * 16 + l16;
#pragma unroll
  for (int r = 0; r < 4; ++r) {
    const int ocr = octile * 16 + quad * 4 + r;
    double a0 = (((double)accI[3][r] * 256.0 + (double)accI[2][r]) * 256.0 +
                 (double)accI[1][r]) * 256.0 + (double)accI[0][r];
    a0 = a0 * (1.0 / 2147483648.0) + (double)bias[ocr];
    double p0d = 1.0 / (1.0 + exp(-a0));
    const int o = ((b * 64 + ocr) * 32 + h) * 32 + w;
    float nx = ((double)u[o] < p0d) ? 1.0f : -1.0f;
    float p0 = (float)p0d;
    float s1 = p0 * (1.0f - p0);
    float s2 = s1 * (1.0f - 2.0f * p0);
    float dq = 2.0f * nx * (s1 * aC1[r] - s2 * aC2[r]);
    out[o] = nx;
    out[262144 + o] = dq;
  }
}

extern "C" void kernel_launch(void* const* d_in, const int* in_sizes, int n_in,
                              void* d_out, int out_size, void* d_ws, size_t ws_size,
                              hipStream_t stream) {
  const float* x      = (const float*)d_in[0];
  const float* q      = (const float*)d_in[1];
  const float* weight = (const float*)d_in[2];
  const float* bias   = (const float*)d_in[3];
  float* out = (float*)d_out;
  char* ws   = (char*)d_ws;

  // prep: 295936 planes + 262144 threefry + 36864 weights = 594944 = 2324*256
  prep_kernel<<<2324, 256, 0, stream>>>(x, q, weight, ws);
  // main: (b*32+h)*2+nt = 256 blocks, 4 waves each (oc-tiles)
  main_kernel<<<256, 256, 0, stream>>>(ws, bias, out);
}

// Round 5
// 75.313 us; speedup vs baseline: 1.7261x; 1.0085x over previous
//
#include <hip/hip_runtime.h>
#include <cstdint>

// Problem: B=4, IC=OC=64, H=W=32, K=3, PAD=1
// Outputs: new_x (262144 f32), new_q (262144 f32) concatenated.
//
//   a0 = conv3x3(x,W,pad=1)+bias ; p0 = sigmoid(a0)
//   new_x = 2*(u < p0) - 1,  u = JAX threefry2x32-20, key=(0,42),
//           partitionable counter mode, draw = out0^out1   [verified r2]
//   new_q = 2*new_x*( s1*C1 - s2*C2 )   [2nd-order Taylor, err ~4e-5 << 2e-2]
//     s1 = p0(1-p0), s2 = s1(1-2p0),
//     C1 = conv3x3(x*q, W), C2 = conv3x3(q, W*W)
//
// Round 5: prep made coalesced (LDS row transpose); threefry inlined into the
// main epilogue (no u plane). a0 path stays EXACT (radix-256 i8 digit GEMMs,
// i32 accum, f64 reconstruction). C1/C2 via bf16 MFMA.
// Fragment layouts (16x16 family, m89/m120-verified):
//   A[m=lane&15][k=quad*(K/4)+j], B[k=quad*(K/4)+j][n=lane&15],
//   C/D: col(n)=lane&15, row(m)=quad*4+reg.

typedef __attribute__((ext_vector_type(4))) int   i32x4;
typedef __attribute__((ext_vector_type(8))) short s16x8;
typedef __attribute__((ext_vector_type(4))) float f32x4;

// ---- ws byte offsets ----
static constexpr int OFF_X8   = 0;          // i8  [b][34][34][64]   295,936 B
static constexpr int OFF_XQH  = 295936;     // bf16[b][34][34][64]   591,872 B
static constexpr int OFF_QH   = 887808;     // bf16[b][34][34][64]   591,872 B
static constexpr int OFF_WD   = 1479680;    // i8  [dig4][tap9][oc64][ic64] 147,456 B
static constexpr int OFF_WB   = 1627136;    // bf16[tap9][oc64][ic64] 73,728 B
static constexpr int OFF_W2B  = 1700864;    // bf16[tap9][oc64][ic64] 73,728 B
// total 1,774,592 B

__device__ __forceinline__ uint32_t rotl32(uint32_t v, int n) {
  return (v << n) | (v >> (32 - n));
}

__device__ __forceinline__ unsigned short f2bf(float f) {
  uint32_t u = __float_as_uint(f);
  uint32_t r = (u + 0x7FFFu + ((u >> 16) & 1u)) >> 16;   // RNE
  return (unsigned short)r;
}

// JAX threefry2x32-20, key=(0,42), partitionable counter mode:
// element j -> counter (0, j); 32-bit draw = out0 ^ out1.  [verified round 2]
__device__ __forceinline__ float threefry_u(uint32_t j) {
  uint32_t x0 = 0u, x1 = j;
  const uint32_t ks1 = 42u, ks2 = 0x1BD11BDAu ^ 42u;
  x0 += 0u; x1 += ks1;
#define QR(rot) { x0 += x1; x1 = rotl32(x1, rot); x1 ^= x0; }
  QR(13) QR(15) QR(26) QR(6)
  x0 += ks1; x1 += ks2 + 1u;
  QR(17) QR(29) QR(16) QR(24)
  x0 += ks2; x1 += 0u + 2u;
  QR(13) QR(15) QR(26) QR(6)
  x0 += 0u; x1 += ks1 + 3u;
  QR(17) QR(29) QR(16) QR(24)
  x0 += ks1; x1 += ks2 + 4u;
  QR(13) QR(15) QR(26) QR(6)
  x0 += ks2; x1 += 0u + 5u;
#undef QR
  uint32_t bits = x0 ^ x1;
  return __uint_as_float((bits >> 9) | 0x3F800000u) - 1.0f;
}

// ---------------- prep ---------------------------------------------------------------
// blocks 0..127   : interior row (b=blk>>5, h=blk&31) — coalesced read, LDS transpose,
//                   contiguous row write
// blocks 128..131 : border zeros for b = blk-128
// blocks 132..275 : weight digitization, k = (blk-132)*256 + tid
__global__ __launch_bounds__(256) void prep_kernel(
    const float* __restrict__ x, const float* __restrict__ q,
    const float* __restrict__ weight, char* __restrict__ ws) {
  const int blk = blockIdx.x;
  const int tid = threadIdx.x;

  if (blk < 128) {
    const int b = blk >> 5;
    const int h = blk & 31;
    __shared__ char           x8s[2048];   // [w][ic]
    __shared__ unsigned short xqs[2048];
    __shared__ unsigned short qs [2048];
    // thread t: ic = t>>2, 8 consecutive w at (t&3)*8 — 128B-contig per 4 lanes
    const int ic = tid >> 2;
    const int w0 = (tid & 3) * 8;
    const int src = ((b * 64 + ic) * 32 + h) * 32 + w0;
    float4 xa = *(const float4*)(x + src);
    float4 xb = *(const float4*)(x + src + 4);
    float4 qa = *(const float4*)(q + src);
    float4 qb = *(const float4*)(q + src + 4);
    float xv[8] = {xa.x, xa.y, xa.z, xa.w, xb.x, xb.y, xb.z, xb.w};
    float qv[8] = {qa.x, qa.y, qa.z, qa.w, qb.x, qb.y, qb.z, qb.w};
#pragma unroll
    for (int j = 0; j < 8; ++j) {
      int a = (w0 + j) * 64 + ic;
      x8s[a] = (char)(int)xv[j];
      xqs[a] = f2bf(xv[j] * qv[j]);
      qs[a]  = f2bf(qv[j]);
    }
    __syncthreads();
    // dest row [b][h+1][1..32][ic]: 2048 contiguous elements
    const int rowel = ((b * 34 + h + 1) * 34 + 1) * 64;
    ((uint2*)(ws + OFF_X8 + rowel))[tid]      = ((const uint2*)x8s)[tid];
    ((uint4*)(ws + OFF_XQH + rowel * 2))[tid] = ((const uint4*)xqs)[tid];
    ((uint4*)(ws + OFF_QH  + rowel * 2))[tid] = ((const uint4*)qs)[tid];
  } else if (blk < 132) {
    const int b = blk - 128;
    // 132 border cells x 64 ic = 8448 elements
    for (int k = tid; k < 8448; k += 256) {
      int cell = k >> 6;
      int ic = k & 63;
      int hp, wp;
      if (cell < 34)       { hp = 0;          wp = cell; }
      else if (cell < 68)  { hp = 33;         wp = cell - 34; }
      else if (cell < 100) { hp = cell - 67;  wp = 0; }       // 1..32
      else                 { hp = cell - 99;  wp = 33; }      // 1..32
      int a = ((b * 34 + hp) * 34 + wp) * 64 + ic;
      ((char*)(ws + OFF_X8))[a] = 0;
      ((unsigned short*)(ws + OFF_XQH))[a] = 0;
      ((unsigned short*)(ws + OFF_QH))[a]  = 0;
    }
  } else {
    // weights: k = tap*4096 + oc*64 + ic
    int k  = (blk - 132) * 256 + tid;      // < 36864
    int ic = k & 63;
    int t  = k >> 6;
    int oc  = t & 63;
    int tap = t >> 6;
    int kh = tap / 3, kw = tap % 3;
    float Wv = weight[((oc * 64 + ic) * 3 + kh) * 3 + kw];
    long long wi = llrint((double)Wv * 2147483648.0);   // round(W*2^31), |wi|<2^28
    char* wd = ws + OFF_WD;
#pragma unroll
    for (int dig = 0; dig < 4; ++dig) {
      signed char d = (signed char)(wi & 0xFF);          // balanced low byte
      wd[dig * 36864 + k] = d;
      wi = (wi - (long long)d) >> 8;
    }
    ((unsigned short*)(ws + OFF_WB))[k]  = f2bf(Wv);
    ((unsigned short*)(ws + OFF_W2B))[k] = f2bf(Wv * Wv);
  }
}

// ---------------- main: MFMA convs + f64 sigmoid + inline threefry ------------------
// grid 256 = (b*32 + h)*2 + nt ; block 256 = 4 waves, wave = oc-tile (16 oc)
__global__ __launch_bounds__(256) void main_kernel(
    const char* __restrict__ ws, const float* __restrict__ bias,
    float* __restrict__ out) {
  const char* x8            = ws + OFF_X8;
  const unsigned short* xqh = (const unsigned short*)(ws + OFF_XQH);
  const unsigned short* qh  = (const unsigned short*)(ws + OFF_QH);
  const char* wd            = ws + OFF_WD;
  const unsigned short* wb  = (const unsigned short*)(ws + OFF_WB);
  const unsigned short* w2b = (const unsigned short*)(ws + OFF_W2B);

  const int b  = blockIdx.x >> 6;
  const int h  = (blockIdx.x >> 1) & 31;
  const int nt = blockIdx.x & 1;

  const int octile = threadIdx.x >> 6;
  const int lane   = threadIdx.x & 63;
  const int quad   = lane >> 4;
  const int l16    = lane & 15;

  i32x4 accI[4];
#pragma unroll
  for (int d = 0; d < 4; ++d) accI[d] = (i32x4){0, 0, 0, 0};
  f32x4 aC1 = {0.f, 0.f, 0.f, 0.f};
  f32x4 aC2 = {0.f, 0.f, 0.f, 0.f};

  const int aoff_i8 = (octile * 16 + l16) * 64 + quad * 16;   // bytes
  const int aoff_bf = (octile * 16 + l16) * 64 + quad * 8;    // ushort elems

#pragma unroll
  for (int kh = 0; kh < 3; ++kh) {
#pragma unroll
    for (int kw = 0; kw < 3; ++kw) {
      const int tap = kh * 3 + kw;
      i32x4 aI[4];
#pragma unroll
      for (int d = 0; d < 4; ++d)
        aI[d] = *(const i32x4*)(wd + d * 36864 + tap * 4096 + aoff_i8);
      s16x8 aW0 = *(const s16x8*)(wb  + tap * 4096 + aoff_bf);
      s16x8 aW1 = *(const s16x8*)(wb  + tap * 4096 + aoff_bf + 32);
      s16x8 aV0 = *(const s16x8*)(w2b + tap * 4096 + aoff_bf);
      s16x8 aV1 = *(const s16x8*)(w2b + tap * 4096 + aoff_bf + 32);
      const int pix = ((b * 34 + h + kh) * 34 + (nt * 16 + l16 + kw)) * 64;
      i32x4 bI  = *(const i32x4*)(x8 + pix + quad * 16);
      s16x8 bX0 = *(const s16x8*)(xqh + pix + quad * 8);
      s16x8 bX1 = *(const s16x8*)(xqh + pix + 32 + quad * 8);
      s16x8 bQ0 = *(const s16x8*)(qh  + pix + quad * 8);
      s16x8 bQ1 = *(const s16x8*)(qh  + pix + 32 + quad * 8);
#pragma unroll
      for (int d = 0; d < 4; ++d)
        accI[d] = __builtin_amdgcn_mfma_i32_16x16x64_i8(aI[d], bI, accI[d], 0, 0, 0);
      aC1 = __builtin_amdgcn_mfma_f32_16x16x32_bf16(aW0, bX0, aC1, 0, 0, 0);
      aC1 = __builtin_amdgcn_mfma_f32_16x16x32_bf16(aW1, bX1, aC1, 0, 0, 0);
      aC2 = __builtin_amdgcn_mfma_f32_16x16x32_bf16(aV0, bQ0, aC2, 0, 0, 0);
      aC2 = __builtin_amdgcn_mfma_f32_16x16x32_bf16(aV1, bQ1, aC2, 0, 0, 0);
    }
  }

  // ---- epilogue: C/D col(n=px)=l16, row(m=oc)=quad*4+r ----
  const int w = nt * 16 + l16;
#pragma unroll
  for (int r = 0; r < 4; ++r) {
    const int ocr = octile * 16 + quad * 4 + r;
    double a0 = (((double)accI[3][r] * 256.0 + (double)accI[2][r]) * 256.0 +
                 (double)accI[1][r]) * 256.0 + (double)accI[0][r];
    a0 = a0 * (1.0 / 2147483648.0) + (double)bias[ocr];
    double p0d = 1.0 / (1.0 + exp(-a0));
    const int o = ((b * 64 + ocr) * 32 + h) * 32 + w;
    float su = threefry_u((uint32_t)o);
    float nx = ((double)su < p0d) ? 1.0f : -1.0f;
    float p0 = (float)p0d;
    float s1 = p0 * (1.0f - p0);
    float s2 = s1 * (1.0f - 2.0f * p0);
    float dq = 2.0f * nx * (s1 * aC1[r] - s2 * aC2[r]);
    out[o] = nx;
    out[262144 + o] = dq;
  }
}

extern "C" void kernel_launch(void* const* d_in, const int* in_sizes, int n_in,
                              void* d_out, int out_size, void* d_ws, size_t ws_size,
                              hipStream_t stream) {
  const float* x      = (const float*)d_in[0];
  const float* q      = (const float*)d_in[1];
  const float* weight = (const float*)d_in[2];
  const float* bias   = (const float*)d_in[3];
  float* out = (float*)d_out;
  char* ws   = (char*)d_ws;

  // prep: 128 row blocks + 4 border blocks + 144 weight blocks = 276
  prep_kernel<<<276, 256, 0, stream>>>(x, q, weight, ws);
  // main: (b*32+h)*2+nt = 256 blocks, 4 waves each (oc-tiles)
  main_kernel<<<256, 256, 0, stream>>>(ws, bias, out);
}